// Round 22
// baseline (404.609 us; speedup 1.0000x reference)
//
#include <hip/hip_runtime.h>
#include <math.h>

typedef _Float16 f16;
typedef _Float16 f16x8 __attribute__((ext_vector_type(8)));
typedef float f32x4 __attribute__((ext_vector_type(4)));

// ---------------- Swin block constants (match reference) ----------------
namespace {
constexpr int Hh = 128, Ww = 128, Cc = 192;
constexpr int NHh = 6;
constexpr int Nn = 64, HDd = 32;
constexpr int SH = 4;
constexpr int Mrows = 131072;
constexpr int NWINtot = 2048;
constexpr float LNEPS = 1e-5f;
constexpr float QSCALE = 0.17677669529663687f;  // 32^-0.5
}

// async 16B global->LDS: lane l writes ldsbase + l*16, per-lane global src
__device__ __forceinline__ void ldsload16(const void* g, void* l) {
  __builtin_amdgcn_global_load_lds(
      (const __attribute__((address_space(1))) void*)g,
      (__attribute__((address_space(3))) void*)l, 16, 0, 0);
}

// windowed row m -> original token index (undo roll -4,-4)
__device__ __forceinline__ int win_row_to_src(int m) {
  int tok = m & 63;
  int wi  = m >> 6;
  int ww = wi & 15, wh = (wi >> 4) & 15, b = wi >> 8;
  int r = (wh << 3) + (tok >> 3);
  int c = (ww << 3) + (tok & 7);
  int ro = (r + SH) & (Hh - 1);
  int co = (c + SH) & (Ww - 1);
  return (b << 14) + (ro << 7) + co;
}

// ---------------- fused LN + fp16 convert + window gather (LN1 path only) ----------------
template <int GATHER>
__global__ __launch_bounds__(256) void ln_prep_kernel(
    const float* __restrict__ X, const float* __restrict__ lnw,
    const float* __restrict__ lnb, f16* __restrict__ outh, int m0) {
  __shared__ float xr[16][192];
  __shared__ float smu[16], srs[16];
  __shared__ int src[16];
  const int t = threadIdx.x;
  const int r0 = blockIdx.x * 16;
  if (t < 16) {
    int m = m0 + r0 + t;
    src[t] = GATHER ? win_row_to_src(m) : m;
  }
  __syncthreads();
#pragma unroll
  for (int it = 0; it < 3; ++it) {
    int f = t + it * 256;
    int row = f / 48, c4 = f - row * 48;
    float4 v = *(const float4*)&X[(size_t)src[row] * 192 + c4 * 4];
    *(float4*)&xr[row][c4 * 4] = v;
  }
  __syncthreads();
  {
    const int lane = t & 63, w = t >> 6;
    const int g = lane >> 4, li = lane & 15;
    const int row = w * 4 + g;
    float s = 0.f, s2 = 0.f;
#pragma unroll
    for (int j = 0; j < 12; ++j) {
      float v = xr[row][li + j * 16];
      s += v; s2 += v * v;
    }
#pragma unroll
    for (int off = 1; off < 16; off <<= 1) {
      s += __shfl_xor(s, off);
      s2 += __shfl_xor(s2, off);
    }
    if (li == 0) {
      float m = s * (1.f / 192.f);
      smu[row] = m;
      srs[row] = rsqrtf(s2 * (1.f / 192.f) - m * m + LNEPS);
    }
  }
  __syncthreads();
#pragma unroll
  for (int it = 0; it < 2; ++it) {
    int c = t + it * 256;
    if (c < 384) {
      int e0 = c * 8;
      int row = e0 / 192, col = e0 - row * 192;
      float mu_ = smu[row], rs_ = srs[row];
      f16x8 o;
#pragma unroll
      for (int j = 0; j < 8; ++j) {
        float v = (xr[row][col + j] - mu_) * rs_ * lnw[col + j] + lnb[col + j];
        o[j] = (f16)v;
      }
      *(f16x8*)&outh[(size_t)(m0 + r0) * 192 + e0] = o;
    }
  }
}

// ---------------- rel-pos bias in MFMA fragment layout: [h][it][jt][lane][r] ----------------
__global__ __launch_bounds__(256) void rpb_expand_kernel(
    const float* __restrict__ rpb, float* __restrict__ biasF2) {
  int t = blockIdx.x * 256 + threadIdx.x;
  if (t >= NHh * 4 * 4 * 64 * 4) return;
  int r = t & 3, lane = (t >> 2) & 63, jt = (t >> 8) & 3, it = (t >> 10) & 3, h = t >> 12;
  int row = it * 16 + (lane >> 4) * 4 + r;
  int col = jt * 16 + (lane & 15);
  int dh = (row >> 3) - (col >> 3) + 7;
  int dw = (row & 7) - (col & 7) + 7;
  biasF2[t] = rpb[(dh * 15 + dw) * NHh + h];
}

// ---------------- weight -> fragment-major fp16 blobs ----------------
__global__ __launch_bounds__(256) void wconv_frag(
    const float* __restrict__ W, f16* __restrict__ Wf, int K, int N) {
  int tid = blockIdx.x * 256 + threadIdx.x;
  if (tid >= K * N) return;
  int e = tid & 7, lane = (tid >> 3) & 63, f = tid >> 9;
  int NKT = K >> 5;
  int kt = f % NKT, nt = f / NKT;
  int k = kt * 32 + ((lane >> 4) << 3) + e;
  int n = nt * 16 + (lane & 15);
  Wf[tid] = (f16)W[(size_t)k * N + n];
}

// ---------------- MFMA GEMM (R7 schedule): LDS A panel, frag-major B loads ----------------
template <int KDIM, int NDIM, int EMODE>
__global__ __launch_bounds__(512, 2) void gemm_mfma16(
    const f16* __restrict__ Abase, const f16* __restrict__ Bf,
    const float* __restrict__ bias, const float* __restrict__ resid,
    void* __restrict__ outp, int m0a, int m0e, int nbx) {
  constexpr int NCH = KDIM / 192;
  constexpr int NKT = KDIM / 32;
  __shared__ __align__(16) char lds[48 * 1024];  // [ks 6][g 8] subtiles 16r x 32k

  const int tid = threadIdx.x;
  const int lane = tid & 63;
  const int wid = tid >> 6;
  const int wr = wid & 1, wc = wid >> 1;
  const int l15 = lane & 15, g2 = lane >> 4;

  int b = blockIdx.x;
  const int nb = gridDim.x;
  if ((nb & 7) == 0) b = (b & 7) * (nb >> 3) + (b >> 3);  // XCD chunked bijection
  const int bx = b % nbx;
  const int by = b / nbx;
  const int bn = bx * 192;
  const int bm = by * 128;
  const int nt0 = bx * 12 + wc * 3;  // N-tile base for this wave

  const int srow = tid >> 2;
  const int kq = tid & 3;
  const int sg = srow >> 4;
  const int slot = srow & 15;
  const f16* arow = Abase + (size_t)(m0a + bm + srow) * KDIM;

  f32x4 acc[4][3];
#pragma unroll
  for (int i = 0; i < 4; ++i)
#pragma unroll
    for (int j = 0; j < 3; ++j) acc[i][j] = (f32x4){0.f, 0.f, 0.f, 0.f};

  for (int c = 0; c < NCH; ++c) {
    if (c) __syncthreads();
#pragma unroll
    for (int u = 0; u < 6; ++u) {
      int ch = kq + u * 4;  // 16B k-chunk 0..23
      f16x8 v = *(const f16x8*)&arow[c * 192 + ch * 8];
      int ks = ch >> 2, h = ch & 3;
      *(f16x8*)(lds + (ks * 8 + sg) * 1024 + (slot + h * 16) * 16) = v;
    }
    __syncthreads();

#pragma unroll
    for (int ks = 0; ks < 6; ++ks) {
      f16x8 bf[3];
#pragma unroll
      for (int ni = 0; ni < 3; ++ni)
        bf[ni] = *(const f16x8*)&Bf[
            (((size_t)(nt0 + ni) * NKT + (c * 6 + ks)) << 9) + (lane << 3)];
#pragma unroll
      for (int mi = 0; mi < 4; ++mi) {
        f16x8 ah = *(const f16x8*)(lds + (ks * 8 + wr * 4 + mi) * 1024 + lane * 16);
#pragma unroll
        for (int ni = 0; ni < 3; ++ni)
          acc[mi][ni] = __builtin_amdgcn_mfma_f32_16x16x32_f16(ah, bf[ni], acc[mi][ni], 0, 0, 0);
      }
    }
  }

#pragma unroll
  for (int mi = 0; mi < 4; ++mi) {
#pragma unroll
    for (int ni = 0; ni < 3; ++ni) {
      int col = bn + wc * 48 + ni * 16 + l15;
      float bcol = bias[col];
#pragma unroll
      for (int r = 0; r < 4; ++r) {
        int ml = bm + wr * 64 + mi * 16 + g2 * 4 + r;
        ((f16*)outp)[(size_t)ml * NDIM + col] = (f16)(acc[mi][ni][r] + bcol);
      }
    }
  }
}

// ---------------- fused LN2 + MLP: cross-chunk interleave (fc2(hc) || fc1(hc+1)) ----------------
// Double-buffered ldsH (72KB LDS -> 2 blocks/CU); per iteration ONE dense
// 144-MFMA region (fc2 of chunk hc + fc1 of chunk hc+1) followed by gelu and a
// single barrier: 5 barriers total vs 9, no isolated fc2 phase.
// Hazard: fc2(hc-1) reads buf (hc+1)&1 complete before barrier(end iter hc-1),
// which precedes gelu(hc+1)'s write to that buf in iter hc.
__global__ __launch_bounds__(256, 2) void mlp_fused(
    const f16* __restrict__ W1f, const f16* __restrict__ W2f,
    const float* __restrict__ b1, const float* __restrict__ b2,
    const float* __restrict__ lnw, const float* __restrict__ lnb,
    float* __restrict__ out) {
  __shared__ __align__(16) char ldsA[24 * 1024];      // [ks 6][g 4] subtiles 16r x 32k
  __shared__ __align__(16) char ldsH[2][24 * 1024];   // double-buffered h1 chunk

  const int tid = threadIdx.x;
  const int lane = tid & 63;
  const int wc = tid >> 6;             // N-quarter 0..3
  const int l15 = lane & 15, g2 = lane >> 4;
  const int bm = blockIdx.x * 64;

  // ---- fused LN2 staging ----
  {
    const float* rowp = out + (size_t)(bm + wc * 16 + l15) * 192 + g2 * 8;
    float vals[48];
    float s = 0.f, s2 = 0.f;
#pragma unroll
    for (int ks = 0; ks < 6; ++ks) {
      float4 a = *(const float4*)&rowp[ks * 32];
      float4 b = *(const float4*)&rowp[ks * 32 + 4];
      float* vp = &vals[ks * 8];
      vp[0] = a.x; vp[1] = a.y; vp[2] = a.z; vp[3] = a.w;
      vp[4] = b.x; vp[5] = b.y; vp[6] = b.z; vp[7] = b.w;
#pragma unroll
      for (int e = 0; e < 8; ++e) { s += vp[e]; s2 += vp[e] * vp[e]; }
    }
    s += __shfl_xor(s, 16);  s2 += __shfl_xor(s2, 16);
    s += __shfl_xor(s, 32);  s2 += __shfl_xor(s2, 32);
    float mu = s * (1.f / 192.f);
    float rs = rsqrtf(s2 * (1.f / 192.f) - mu * mu + LNEPS);
#pragma unroll
    for (int ks = 0; ks < 6; ++ks) {
      f16x8 o;
#pragma unroll
      for (int e = 0; e < 8; ++e) {
        int k = ks * 32 + g2 * 8 + e;
        o[e] = (f16)((vals[ks * 8 + e] - mu) * rs * lnw[k] + lnb[k]);
      }
      *(f16x8*)(ldsA + (ks * 4 + wc) * 1024 + lane * 16) = o;
    }
  }

  f32x4 acc2[4][3];
#pragma unroll
  for (int i = 0; i < 4; ++i)
#pragma unroll
    for (int j = 0; j < 3; ++j) acc2[i][j] = (f32x4){0.f, 0.f, 0.f, 0.f};

  __syncthreads();  // publish A

  // ---- helper lambdas expanded inline: gelu+store to ldsH[buf] ----
  // prologue: fc1(0) -> gelu -> ldsH[0]
  {
    f32x4 acc1[4][3];
#pragma unroll
    for (int i = 0; i < 4; ++i)
#pragma unroll
      for (int j = 0; j < 3; ++j) acc1[i][j] = (f32x4){0.f, 0.f, 0.f, 0.f};
#pragma unroll
    for (int ks = 0; ks < 6; ++ks) {
      f16x8 w1[3];
#pragma unroll
      for (int ni = 0; ni < 3; ++ni)
        w1[ni] = *(const f16x8*)&W1f[
            (((size_t)(0 * 12 + wc * 3 + ni) * 6 + ks) << 9) + (lane << 3)];
#pragma unroll
      for (int mi = 0; mi < 4; ++mi) {
        f16x8 ah = *(const f16x8*)(ldsA + (ks * 4 + mi) * 1024 + lane * 16);
#pragma unroll
        for (int ni = 0; ni < 3; ++ni)
          acc1[mi][ni] = __builtin_amdgcn_mfma_f32_16x16x32_f16(ah, w1[ni], acc1[mi][ni], 0, 0, 0);
      }
    }
#pragma unroll
    for (int mi = 0; mi < 4; ++mi)
#pragma unroll
      for (int ni = 0; ni < 3; ++ni) {
        float bcol = b1[0 * 192 + wc * 48 + ni * 16 + l15];
#pragma unroll
        for (int r = 0; r < 4; ++r) {
          float v = acc1[mi][ni][r] + bcol;
          float u = v * (1.f + 0.044715f * v * v);
          float ex = __expf(-1.5957691216f * u);
          v = v * __builtin_amdgcn_rcpf(1.f + ex);
          int row = mi * 16 + g2 * 4 + r;
          int col = wc * 48 + ni * 16 + l15;
          *(f16*)(ldsH[0] + ((col >> 5) * 4 + mi) * 1024 +
                  ((row & 15) + ((col >> 3) & 3) * 16) * 16 + (col & 7) * 2) = (f16)v;
        }
      }
  }
  __syncthreads();  // publish ldsH[0]

  for (int hc = 0; hc < 4; ++hc) {
    const char* cur = ldsH[hc & 1];
    if (hc < 3) {
      // ---- interleaved: fc2(hc) from cur + fc1(hc+1) from ldsA ----
      f32x4 acc1[4][3];
#pragma unroll
      for (int i = 0; i < 4; ++i)
#pragma unroll
        for (int j = 0; j < 3; ++j) acc1[i][j] = (f32x4){0.f, 0.f, 0.f, 0.f};
#pragma unroll
      for (int ks = 0; ks < 6; ++ks) {
        f16x8 w2[3], w1[3];
#pragma unroll
        for (int ni = 0; ni < 3; ++ni) {
          w2[ni] = *(const f16x8*)&W2f[
              (((size_t)(wc * 3 + ni) * 24 + hc * 6 + ks) << 9) + (lane << 3)];
          w1[ni] = *(const f16x8*)&W1f[
              (((size_t)((hc + 1) * 12 + wc * 3 + ni) * 6 + ks) << 9) + (lane << 3)];
        }
#pragma unroll
        for (int mi = 0; mi < 4; ++mi) {
          f16x8 ah2 = *(const f16x8*)(cur + (ks * 4 + mi) * 1024 + lane * 16);
#pragma unroll
          for (int ni = 0; ni < 3; ++ni)
            acc2[mi][ni] = __builtin_amdgcn_mfma_f32_16x16x32_f16(ah2, w2[ni], acc2[mi][ni], 0, 0, 0);
          f16x8 ah1 = *(const f16x8*)(ldsA + (ks * 4 + mi) * 1024 + lane * 16);
#pragma unroll
          for (int ni = 0; ni < 3; ++ni)
            acc1[mi][ni] = __builtin_amdgcn_mfma_f32_16x16x32_f16(ah1, w1[ni], acc1[mi][ni], 0, 0, 0);
        }
      }
      // ---- gelu(hc+1) -> ldsH[(hc+1)&1] (other buffer; no read conflict) ----
      char* nb_ = ldsH[(hc + 1) & 1];
#pragma unroll
      for (int mi = 0; mi < 4; ++mi)
#pragma unroll
        for (int ni = 0; ni < 3; ++ni) {
          float bcol = b1[(hc + 1) * 192 + wc * 48 + ni * 16 + l15];
#pragma unroll
          for (int r = 0; r < 4; ++r) {
            float v = acc1[mi][ni][r] + bcol;
            float u = v * (1.f + 0.044715f * v * v);
            float ex = __expf(-1.5957691216f * u);
            v = v * __builtin_amdgcn_rcpf(1.f + ex);
            int row = mi * 16 + g2 * 4 + r;
            int col = wc * 48 + ni * 16 + l15;
            *(f16*)(nb_ + ((col >> 5) * 4 + mi) * 1024 +
                    ((row & 15) + ((col >> 3) & 3) * 16) * 16 + (col & 7) * 2) = (f16)v;
          }
        }
      __syncthreads();  // publish next buf; fences fc2(hc) reads before next overwrite
    } else {
      // ---- final fc2(3) only ----
#pragma unroll
      for (int ks = 0; ks < 6; ++ks) {
        f16x8 w2[3];
#pragma unroll
        for (int ni = 0; ni < 3; ++ni)
          w2[ni] = *(const f16x8*)&W2f[
              (((size_t)(wc * 3 + ni) * 24 + hc * 6 + ks) << 9) + (lane << 3)];
#pragma unroll
        for (int mi = 0; mi < 4; ++mi) {
          f16x8 ah2 = *(const f16x8*)(cur + (ks * 4 + mi) * 1024 + lane * 16);
#pragma unroll
          for (int ni = 0; ni < 3; ++ni)
            acc2[mi][ni] = __builtin_amdgcn_mfma_f32_16x16x32_f16(ah2, w2[ni], acc2[mi][ni], 0, 0, 0);
        }
      }
    }
  }

  // ---- epilogue: + bias2 + residual in place ----
#pragma unroll
  for (int mi = 0; mi < 4; ++mi)
#pragma unroll
    for (int ni = 0; ni < 3; ++ni) {
      int col = wc * 48 + ni * 16 + l15;
      float bcol = b2[col];
#pragma unroll
      for (int r = 0; r < 4; ++r) {
        int ml = bm + mi * 16 + g2 * 4 + r;
        out[(size_t)ml * 192 + col] = acc2[mi][ni][r] + bcol + out[(size_t)ml * 192 + col];
      }
    }
}

// ---------------- MFMA windowed attention + fused proj: 2 blocks/window, XCD swizzle ----------------
__global__ __launch_bounds__(384) void attn_mfma(
    const f16* __restrict__ qkv, const float* __restrict__ biasF2,
    const f16* __restrict__ Wpf, const float* __restrict__ pb_,
    const float* __restrict__ resid, float* __restrict__ out, int w0) {
  __shared__ f16 Vt[192 * 64];        // [d][tok], 16B-chunk XOR swizzle
  __shared__ f16 Pb[NHh][32 * 64];    // per-wave P (32 q); first 12KB reused as proj-A
  const int t = threadIdx.x;
  const int h = t >> 6;
  const int lane = t & 63;
  const int g = lane >> 4, l15 = lane & 15;
  int b = blockIdx.x;
  const int nb = gridDim.x;
  if ((nb & 7) == 0) b = (b & 7) * (nb >> 3) + (b >> 3);  // XCD chunked bijection
  const int wl = b >> 1;
  const int qh = b & 1;               // query half: rows qh*32 .. +32
  const f16* base = qkv + (size_t)wl * 64 * 576;

  {
    const f16* vr = base + (size_t)lane * 576 + 384 + h * 32;
    f16x8 vv[4];
#pragma unroll
    for (int u = 0; u < 4; ++u) vv[u] = *(const f16x8*)&vr[u * 8];
    const int c = lane >> 3, e7 = lane & 7;
#pragma unroll
    for (int u = 0; u < 4; ++u)
#pragma unroll
      for (int e = 0; e < 8; ++e) {
        int d = h * 32 + u * 8 + e;
        Vt[d * 64 + ((c ^ e) << 3) + e7] = vv[u][e];  // d&7 == e
      }
  }

  f16x8 qf[2], kf[4];
#pragma unroll
  for (int it = 0; it < 2; ++it)
    qf[it] = *(const f16x8*)&base[(size_t)(qh * 32 + it * 16 + l15) * 576 + h * 32 + g * 8];
#pragma unroll
  for (int jt = 0; jt < 4; ++jt)
    kf[jt] = *(const f16x8*)&base[(size_t)(jt * 16 + l15) * 576 + 192 + h * 32 + g * 8];

  f32x4 S[2][4];
#pragma unroll
  for (int it = 0; it < 2; ++it)
#pragma unroll
    for (int jt = 0; jt < 4; ++jt) S[it][jt] = (f32x4){0.f, 0.f, 0.f, 0.f};
#pragma unroll
  for (int it = 0; it < 2; ++it)
#pragma unroll
    for (int jt = 0; jt < 4; ++jt)
      S[it][jt] = __builtin_amdgcn_mfma_f32_16x16x32_f16(qf[it], kf[jt], S[it][jt], 0, 0, 0);

  const int wi = (w0 + wl) & 255;
  const int wh = wi >> 4, wwc = wi & 15;
  int regj[4];
#pragma unroll
  for (int jt = 0; jt < 4; ++jt) {
    int col = jt * 16 + l15;
    int rj = wh * 8 + (col >> 3), cj = wwc * 8 + (col & 7);
    regj[jt] = (rj < 120 ? 0 : rj < 124 ? 1 : 2) * 3 + (cj < 120 ? 0 : cj < 124 ? 1 : 2);
  }
#pragma unroll
  for (int it = 0; it < 2; ++it) {
    const int itg = qh * 2 + it;
    int regi[4];
#pragma unroll
    for (int r = 0; r < 4; ++r) {
      int row = itg * 16 + g * 4 + r;
      int ri = wh * 8 + (row >> 3), ci = wwc * 8 + (row & 7);
      regi[r] = (ri < 120 ? 0 : ri < 124 ? 1 : 2) * 3 + (ci < 120 ? 0 : ci < 124 ? 1 : 2);
    }
#pragma unroll
    for (int jt = 0; jt < 4; ++jt) {
      f32x4 bb = *(const f32x4*)&biasF2[(((h * 4 + itg) * 4 + jt) * 64 + lane) * 4];
#pragma unroll
      for (int r = 0; r < 4; ++r) {
        float v = S[it][jt][r] * QSCALE + bb[r];
        if (regi[r] != regj[jt]) v -= 100.f;
        S[it][jt][r] = v;
      }
    }
  }

#pragma unroll
  for (int it = 0; it < 2; ++it) {
#pragma unroll
    for (int r = 0; r < 4; ++r) {
      float m = fmaxf(fmaxf(S[it][0][r], S[it][1][r]), fmaxf(S[it][2][r], S[it][3][r]));
#pragma unroll
      for (int off = 1; off < 16; off <<= 1) m = fmaxf(m, __shfl_xor(m, off));
#pragma unroll
      for (int jt = 0; jt < 4; ++jt) S[it][jt][r] = __expf(S[it][jt][r] - m);
    }
  }

  f16* pb = &Pb[h][0];
#pragma unroll
  for (int it = 0; it < 2; ++it)
#pragma unroll
    for (int jt = 0; jt < 4; ++jt)
#pragma unroll
      for (int r = 0; r < 4; ++r) {
        int row = it * 16 + g * 4 + r;
        int cs = (jt * 2 + (l15 >> 3)) ^ (row & 7);
        pb[row * 64 + cs * 8 + (l15 & 7)] = (f16)S[it][jt][r];
      }

  f32x4 O[2][2], Ssum[2];
#pragma unroll
  for (int it = 0; it < 2; ++it) {
    O[it][0] = (f32x4){0.f, 0.f, 0.f, 0.f};
    O[it][1] = (f32x4){0.f, 0.f, 0.f, 0.f};
    Ssum[it] = (f32x4){0.f, 0.f, 0.f, 0.f};
  }
  f16x8 ones;
#pragma unroll
  for (int e = 0; e < 8; ++e) ones[e] = (f16)1.f;
#pragma unroll
  for (int jh = 0; jh < 2; ++jh) {
    const int csw = ((jh * 4 + g) ^ (l15 & 7)) << 3;
    f16x8 pf[2], vf[2];
#pragma unroll
    for (int it = 0; it < 2; ++it) pf[it] = *(const f16x8*)&pb[(it * 16 + l15) * 64 + csw];
#pragma unroll
    for (int dt = 0; dt < 2; ++dt) vf[dt] = *(const f16x8*)&Vt[(h * 32 + dt * 16 + l15) * 64 + csw];
#pragma unroll
    for (int it = 0; it < 2; ++it) {
      O[it][0] = __builtin_amdgcn_mfma_f32_16x16x32_f16(pf[it], vf[0], O[it][0], 0, 0, 0);
      O[it][1] = __builtin_amdgcn_mfma_f32_16x16x32_f16(pf[it], vf[1], O[it][1], 0, 0, 0);
      Ssum[it] = __builtin_amdgcn_mfma_f32_16x16x32_f16(pf[it], ones, Ssum[it], 0, 0, 0);
    }
  }

  __syncthreads();

  {
    char* Ao = (char*)&Pb[0][0];
#pragma unroll
    for (int it = 0; it < 2; ++it) {
      f32x4 rin;
#pragma unroll
      for (int r = 0; r < 4; ++r) rin[r] = 1.f / Ssum[it][r];
#pragma unroll
      for (int dt = 0; dt < 2; ++dt) {
        int hh = dt * 2 + (l15 >> 3);
        int e = l15 & 7;
#pragma unroll
        for (int r = 0; r < 4; ++r) {
          *(f16*)(Ao + (h * 2 + it) * 1024 + ((g * 4 + r) + hh * 16) * 16 + e * 2) =
              (f16)(O[it][dt][r] * rin[r]);
        }
      }
    }
  }
  __syncthreads();

  {
    const char* Ao = (const char*)&Pb[0][0];
    f32x4 acc[2][2];
#pragma unroll
    for (int i = 0; i < 2; ++i) {
      acc[i][0] = (f32x4){0.f, 0.f, 0.f, 0.f};
      acc[i][1] = (f32x4){0.f, 0.f, 0.f, 0.f};
    }
#pragma unroll
    for (int ks = 0; ks < 6; ++ks) {
      f16x8 bf[2];
#pragma unroll
      for (int ni = 0; ni < 2; ++ni)
        bf[ni] = *(const f16x8*)&Wpf[(((size_t)(h * 2 + ni) * 6 + ks) << 9) + (lane << 3)];
#pragma unroll
      for (int it = 0; it < 2; ++it) {
        f16x8 ah = *(const f16x8*)(Ao + (ks * 2 + it) * 1024 + lane * 16);
#pragma unroll
        for (int ni = 0; ni < 2; ++ni)
          acc[it][ni] = __builtin_amdgcn_mfma_f32_16x16x32_f16(ah, bf[ni], acc[it][ni], 0, 0, 0);
      }
    }
#pragma unroll
    for (int it = 0; it < 2; ++it)
#pragma unroll
      for (int ni = 0; ni < 2; ++ni) {
        int col = h * 32 + ni * 16 + l15;
        float bcol = pb_[col];
#pragma unroll
        for (int r = 0; r < 4; ++r) {
          int ml = qh * 32 + it * 16 + g * 4 + r;
          int dst = win_row_to_src((w0 + wl) * 64 + ml);
          out[(size_t)dst * 192 + col] = acc[it][ni][r] + bcol + resid[(size_t)dst * 192 + col];
        }
      }
  }
}

// ---------------- host launch ----------------
extern "C" void kernel_launch(void* const* d_in, const int* in_sizes, int n_in,
                              void* d_out, int out_size, void* d_ws, size_t ws_size,
                              hipStream_t stream) {
  const float* x     = (const float*)d_in[0];
  const float* ln1w  = (const float*)d_in[1];
  const float* ln1b  = (const float*)d_in[2];
  const float* qkvw  = (const float*)d_in[3];
  const float* qkvb  = (const float*)d_in[4];
  const float* rpb   = (const float*)d_in[5];
  const float* projw = (const float*)d_in[6];
  const float* projb = (const float*)d_in[7];
  const float* ln2w  = (const float*)d_in[8];
  const float* ln2b  = (const float*)d_in[9];
  const float* fc1w  = (const float*)d_in[10];
  const float* fc1b  = (const float*)d_in[11];
  const float* fc2w  = (const float*)d_in[12];
  const float* fc2b  = (const float*)d_in[13];
  float* out = (float*)d_out;

  // ws layout (B): biasF2 96K | Wf f16 frag-major | xh 48M | big
  char* ws = (char*)d_ws;
  float* biasF2 = (float*)ws;
  f16* qkvwF = (f16*)(ws + 98304);
  f16* projwF = (f16*)(ws + 319488);
  f16* fc1wF = (f16*)(ws + 393216);
  f16* fc2wF = (f16*)(ws + 688128);
  f16* xh    = (f16*)(ws + 983040);
  char* big  = ws + 983040 + 50331648;
  size_t R = ws_size > (size_t)(983040 + 50331648)
                 ? ws_size - (983040 + 50331648) : 0;

  long long wch = (long long)(R / 73728);  // per window: qkv16 only
  if (wch > NWINtot) wch = NWINtot;
  wch &= ~1LL;
  if (wch < 2) wch = 2;

  wconv_frag<<<432, 256, 0, stream>>>(qkvw, qkvwF, 192, 576);
  wconv_frag<<<144, 256, 0, stream>>>(projw, projwF, 192, 192);
  wconv_frag<<<576, 256, 0, stream>>>(fc1w, fc1wF, 192, 768);
  wconv_frag<<<576, 256, 0, stream>>>(fc2w, fc2wF, 768, 192);
  rpb_expand_kernel<<<96, 256, 0, stream>>>(rpb, biasF2);

  ln_prep_kernel<1><<<Mrows / 16, 256, 0, stream>>>(x, ln1w, ln1b, xh, 0);

  f16* qkvc = (f16*)big;
  for (int w = 0; w < NWINtot; w += (int)wch) {
    int cur = (NWINtot - w < (int)wch) ? (NWINtot - w) : (int)wch;
    int ny = cur * 64 / 128;
    gemm_mfma16<192, 576, 0><<<3 * ny, 512, 0, stream>>>(
        xh, qkvwF, qkvb, nullptr, qkvc, w * 64, 0, 3);
    attn_mfma<<<cur * 2, 384, 0, stream>>>(qkvc, biasF2, projwF, projb, x, out, w);
  }

  // fused LN2 + MLP: cross-chunk interleaved schedule
  mlp_fused<<<Mrows / 64, 256, 0, stream>>>(
      fc1wF, fc2wF, fc1b, fc2b, ln2w, ln2b, out);
}

// Round 23
// 350.382 us; speedup vs baseline: 1.1548x; 1.1548x over previous
//
#include <hip/hip_runtime.h>
#include <math.h>

typedef _Float16 f16;
typedef _Float16 f16x8 __attribute__((ext_vector_type(8)));
typedef float f32x4 __attribute__((ext_vector_type(4)));

// ---------------- Swin block constants (match reference) ----------------
namespace {
constexpr int Hh = 128, Ww = 128, Cc = 192;
constexpr int NHh = 6;
constexpr int Nn = 64, HDd = 32;
constexpr int SH = 4;
constexpr int Mrows = 131072;
constexpr int NWINtot = 2048;
constexpr float LNEPS = 1e-5f;
constexpr float QSCALE = 0.17677669529663687f;  // 32^-0.5
}

// async 16B global->LDS: lane l writes ldsbase + l*16, per-lane global src
__device__ __forceinline__ void ldsload16(const void* g, void* l) {
  __builtin_amdgcn_global_load_lds(
      (const __attribute__((address_space(1))) void*)g,
      (__attribute__((address_space(3))) void*)l, 16, 0, 0);
}

// windowed row m -> original token index (undo roll -4,-4)
__device__ __forceinline__ int win_row_to_src(int m) {
  int tok = m & 63;
  int wi  = m >> 6;
  int ww = wi & 15, wh = (wi >> 4) & 15, b = wi >> 8;
  int r = (wh << 3) + (tok >> 3);
  int c = (ww << 3) + (tok & 7);
  int ro = (r + SH) & (Hh - 1);
  int co = (c + SH) & (Ww - 1);
  return (b << 14) + (ro << 7) + co;
}

// ---------------- fused LN + fp16 convert + window gather (LN1 path only) ----------------
template <int GATHER>
__global__ __launch_bounds__(256) void ln_prep_kernel(
    const float* __restrict__ X, const float* __restrict__ lnw,
    const float* __restrict__ lnb, f16* __restrict__ outh, int m0) {
  __shared__ float xr[16][192];
  __shared__ float smu[16], srs[16];
  __shared__ int src[16];
  const int t = threadIdx.x;
  const int r0 = blockIdx.x * 16;
  if (t < 16) {
    int m = m0 + r0 + t;
    src[t] = GATHER ? win_row_to_src(m) : m;
  }
  __syncthreads();
#pragma unroll
  for (int it = 0; it < 3; ++it) {
    int f = t + it * 256;
    int row = f / 48, c4 = f - row * 48;
    float4 v = *(const float4*)&X[(size_t)src[row] * 192 + c4 * 4];
    *(float4*)&xr[row][c4 * 4] = v;
  }
  __syncthreads();
  {
    const int lane = t & 63, w = t >> 6;
    const int g = lane >> 4, li = lane & 15;
    const int row = w * 4 + g;
    float s = 0.f, s2 = 0.f;
#pragma unroll
    for (int j = 0; j < 12; ++j) {
      float v = xr[row][li + j * 16];
      s += v; s2 += v * v;
    }
#pragma unroll
    for (int off = 1; off < 16; off <<= 1) {
      s += __shfl_xor(s, off);
      s2 += __shfl_xor(s2, off);
    }
    if (li == 0) {
      float m = s * (1.f / 192.f);
      smu[row] = m;
      srs[row] = rsqrtf(s2 * (1.f / 192.f) - m * m + LNEPS);
    }
  }
  __syncthreads();
#pragma unroll
  for (int it = 0; it < 2; ++it) {
    int c = t + it * 256;
    if (c < 384) {
      int e0 = c * 8;
      int row = e0 / 192, col = e0 - row * 192;
      float mu_ = smu[row], rs_ = srs[row];
      f16x8 o;
#pragma unroll
      for (int j = 0; j < 8; ++j) {
        float v = (xr[row][col + j] - mu_) * rs_ * lnw[col + j] + lnb[col + j];
        o[j] = (f16)v;
      }
      *(f16x8*)&outh[(size_t)(m0 + r0) * 192 + e0] = o;
    }
  }
}

// ---------------- rel-pos bias in MFMA fragment layout: [h][it][jt][lane][r] ----------------
__global__ __launch_bounds__(256) void rpb_expand_kernel(
    const float* __restrict__ rpb, float* __restrict__ biasF2) {
  int t = blockIdx.x * 256 + threadIdx.x;
  if (t >= NHh * 4 * 4 * 64 * 4) return;
  int r = t & 3, lane = (t >> 2) & 63, jt = (t >> 8) & 3, it = (t >> 10) & 3, h = t >> 12;
  int row = it * 16 + (lane >> 4) * 4 + r;
  int col = jt * 16 + (lane & 15);
  int dh = (row >> 3) - (col >> 3) + 7;
  int dw = (row & 7) - (col & 7) + 7;
  biasF2[t] = rpb[(dh * 15 + dw) * NHh + h];
}

// ---------------- weight -> fragment-major fp16 blobs ----------------
__global__ __launch_bounds__(256) void wconv_frag(
    const float* __restrict__ W, f16* __restrict__ Wf, int K, int N) {
  int tid = blockIdx.x * 256 + threadIdx.x;
  if (tid >= K * N) return;
  int e = tid & 7, lane = (tid >> 3) & 63, f = tid >> 9;
  int NKT = K >> 5;
  int kt = f % NKT, nt = f / NKT;
  int k = kt * 32 + ((lane >> 4) << 3) + e;
  int n = nt * 16 + (lane & 15);
  Wf[tid] = (f16)W[(size_t)k * N + n];
}

// ---------------- MFMA GEMM (R7 schedule): LDS A panel, frag-major B loads ----------------
template <int KDIM, int NDIM, int EMODE>
__global__ __launch_bounds__(512, 2) void gemm_mfma16(
    const f16* __restrict__ Abase, const f16* __restrict__ Bf,
    const float* __restrict__ bias, const float* __restrict__ resid,
    void* __restrict__ outp, int m0a, int m0e, int nbx) {
  constexpr int NCH = KDIM / 192;
  constexpr int NKT = KDIM / 32;
  __shared__ __align__(16) char lds[48 * 1024];  // [ks 6][g 8] subtiles 16r x 32k

  const int tid = threadIdx.x;
  const int lane = tid & 63;
  const int wid = tid >> 6;
  const int wr = wid & 1, wc = wid >> 1;
  const int l15 = lane & 15, g2 = lane >> 4;

  int b = blockIdx.x;
  const int nb = gridDim.x;
  if ((nb & 7) == 0) b = (b & 7) * (nb >> 3) + (b >> 3);  // XCD chunked bijection
  const int bx = b % nbx;
  const int by = b / nbx;
  const int bn = bx * 192;
  const int bm = by * 128;
  const int nt0 = bx * 12 + wc * 3;  // N-tile base for this wave

  const int srow = tid >> 2;
  const int kq = tid & 3;
  const int sg = srow >> 4;
  const int slot = srow & 15;
  const f16* arow = Abase + (size_t)(m0a + bm + srow) * KDIM;

  f32x4 acc[4][3];
#pragma unroll
  for (int i = 0; i < 4; ++i)
#pragma unroll
    for (int j = 0; j < 3; ++j) acc[i][j] = (f32x4){0.f, 0.f, 0.f, 0.f};

  for (int c = 0; c < NCH; ++c) {
    if (c) __syncthreads();
#pragma unroll
    for (int u = 0; u < 6; ++u) {
      int ch = kq + u * 4;  // 16B k-chunk 0..23
      f16x8 v = *(const f16x8*)&arow[c * 192 + ch * 8];
      int ks = ch >> 2, h = ch & 3;
      *(f16x8*)(lds + (ks * 8 + sg) * 1024 + (slot + h * 16) * 16) = v;
    }
    __syncthreads();

#pragma unroll
    for (int ks = 0; ks < 6; ++ks) {
      f16x8 bf[3];
#pragma unroll
      for (int ni = 0; ni < 3; ++ni)
        bf[ni] = *(const f16x8*)&Bf[
            (((size_t)(nt0 + ni) * NKT + (c * 6 + ks)) << 9) + (lane << 3)];
#pragma unroll
      for (int mi = 0; mi < 4; ++mi) {
        f16x8 ah = *(const f16x8*)(lds + (ks * 8 + wr * 4 + mi) * 1024 + lane * 16);
#pragma unroll
        for (int ni = 0; ni < 3; ++ni)
          acc[mi][ni] = __builtin_amdgcn_mfma_f32_16x16x32_f16(ah, bf[ni], acc[mi][ni], 0, 0, 0);
      }
    }
  }

#pragma unroll
  for (int mi = 0; mi < 4; ++mi) {
#pragma unroll
    for (int ni = 0; ni < 3; ++ni) {
      int col = bn + wc * 48 + ni * 16 + l15;
      float bcol = bias[col];
#pragma unroll
      for (int r = 0; r < 4; ++r) {
        int ml = bm + wr * 64 + mi * 16 + g2 * 4 + r;
        ((f16*)outp)[(size_t)ml * NDIM + col] = (f16)(acc[mi][ni][r] + bcol);
      }
    }
  }
}

// ---------------- fused LN2 + MLP (R17/R20 4-wave version — measured optimum) ----------------
// Block = 64 rows, 256 thr = 4 waves. LN2 folded into A-staging; frag-major
// weights; 48KB LDS -> 3 blocks/CU; VGPR 84, zero spill. 157us measured.
__global__ __launch_bounds__(256, 2) void mlp_fused(
    const f16* __restrict__ W1f, const f16* __restrict__ W2f,
    const float* __restrict__ b1, const float* __restrict__ b2,
    const float* __restrict__ lnw, const float* __restrict__ lnb,
    float* __restrict__ out) {
  __shared__ __align__(16) char ldsA[24 * 1024];  // [ks 6][g 4] subtiles 16r x 32k
  __shared__ __align__(16) char ldsH[24 * 1024];

  const int tid = threadIdx.x;
  const int lane = tid & 63;
  const int wc = tid >> 6;             // N-quarter 0..3
  const int l15 = lane & 15, g2 = lane >> 4;
  const int bm = blockIdx.x * 64;

  // ---- fused LN2 staging ----
  {
    const float* rowp = out + (size_t)(bm + wc * 16 + l15) * 192 + g2 * 8;
    float vals[48];
    float s = 0.f, s2 = 0.f;
#pragma unroll
    for (int ks = 0; ks < 6; ++ks) {
      float4 a = *(const float4*)&rowp[ks * 32];
      float4 b = *(const float4*)&rowp[ks * 32 + 4];
      float* vp = &vals[ks * 8];
      vp[0] = a.x; vp[1] = a.y; vp[2] = a.z; vp[3] = a.w;
      vp[4] = b.x; vp[5] = b.y; vp[6] = b.z; vp[7] = b.w;
#pragma unroll
      for (int e = 0; e < 8; ++e) { s += vp[e]; s2 += vp[e] * vp[e]; }
    }
    s += __shfl_xor(s, 16);  s2 += __shfl_xor(s2, 16);
    s += __shfl_xor(s, 32);  s2 += __shfl_xor(s2, 32);
    float mu = s * (1.f / 192.f);
    float rs = rsqrtf(s2 * (1.f / 192.f) - mu * mu + LNEPS);
#pragma unroll
    for (int ks = 0; ks < 6; ++ks) {
      f16x8 o;
#pragma unroll
      for (int e = 0; e < 8; ++e) {
        int k = ks * 32 + g2 * 8 + e;
        o[e] = (f16)((vals[ks * 8 + e] - mu) * rs * lnw[k] + lnb[k]);
      }
      *(f16x8*)(ldsA + (ks * 4 + wc) * 1024 + lane * 16) = o;
    }
  }

  f32x4 acc2[4][3];
#pragma unroll
  for (int i = 0; i < 4; ++i)
#pragma unroll
    for (int j = 0; j < 3; ++j) acc2[i][j] = (f32x4){0.f, 0.f, 0.f, 0.f};

  __syncthreads();  // publish A

  for (int hc = 0; hc < 4; ++hc) {
    f32x4 acc1[4][3];
#pragma unroll
    for (int i = 0; i < 4; ++i)
#pragma unroll
      for (int j = 0; j < 3; ++j) acc1[i][j] = (f32x4){0.f, 0.f, 0.f, 0.f};
#pragma unroll
    for (int ks = 0; ks < 6; ++ks) {
      f16x8 bf[3];
#pragma unroll
      for (int ni = 0; ni < 3; ++ni)
        bf[ni] = *(const f16x8*)&W1f[
            (((size_t)(hc * 12 + wc * 3 + ni) * 6 + ks) << 9) + (lane << 3)];
#pragma unroll
      for (int mi = 0; mi < 4; ++mi) {
        f16x8 ah = *(const f16x8*)(ldsA + (ks * 4 + mi) * 1024 + lane * 16);
#pragma unroll
        for (int ni = 0; ni < 3; ++ni)
          acc1[mi][ni] = __builtin_amdgcn_mfma_f32_16x16x32_f16(ah, bf[ni], acc1[mi][ni], 0, 0, 0);
      }
    }
#pragma unroll
    for (int mi = 0; mi < 4; ++mi)
#pragma unroll
      for (int ni = 0; ni < 3; ++ni) {
        float bcol = b1[hc * 192 + wc * 48 + ni * 16 + l15];
#pragma unroll
        for (int r = 0; r < 4; ++r) {
          float v = acc1[mi][ni][r] + bcol;
          float u = v * (1.f + 0.044715f * v * v);
          float ex = __expf(-1.5957691216f * u);
          v = v * __builtin_amdgcn_rcpf(1.f + ex);
          int row = mi * 16 + g2 * 4 + r;
          int col = wc * 48 + ni * 16 + l15;
          *(f16*)(ldsH + ((col >> 5) * 4 + mi) * 1024 +
                  ((row & 15) + ((col >> 3) & 3) * 16) * 16 + (col & 7) * 2) = (f16)v;
        }
      }
    __syncthreads();  // h1c visible

#pragma unroll
    for (int ks = 0; ks < 6; ++ks) {
      f16x8 bf[3];
#pragma unroll
      for (int ni = 0; ni < 3; ++ni)
        bf[ni] = *(const f16x8*)&W2f[
            (((size_t)(wc * 3 + ni) * 24 + hc * 6 + ks) << 9) + (lane << 3)];
#pragma unroll
      for (int mi = 0; mi < 4; ++mi) {
        f16x8 ah = *(const f16x8*)(ldsH + (ks * 4 + mi) * 1024 + lane * 16);
#pragma unroll
        for (int ni = 0; ni < 3; ++ni)
          acc2[mi][ni] = __builtin_amdgcn_mfma_f32_16x16x32_f16(ah, bf[ni], acc2[mi][ni], 0, 0, 0);
      }
    }
    __syncthreads();  // protect ldsH before next chunk overwrites
  }

#pragma unroll
  for (int mi = 0; mi < 4; ++mi)
#pragma unroll
    for (int ni = 0; ni < 3; ++ni) {
      int col = wc * 48 + ni * 16 + l15;
      float bcol = b2[col];
#pragma unroll
      for (int r = 0; r < 4; ++r) {
        int ml = bm + mi * 16 + g2 * 4 + r;
        out[(size_t)ml * 192 + col] = acc2[mi][ni][r] + bcol + out[(size_t)ml * 192 + col];
      }
    }
}

// ---------------- MFMA windowed attention + fused proj: 2 blocks/window, XCD swizzle ----------------
__global__ __launch_bounds__(384) void attn_mfma(
    const f16* __restrict__ qkv, const float* __restrict__ biasF2,
    const f16* __restrict__ Wpf, const float* __restrict__ pb_,
    const float* __restrict__ resid, float* __restrict__ out, int w0) {
  __shared__ f16 Vt[192 * 64];        // [d][tok], 16B-chunk XOR swizzle
  __shared__ f16 Pb[NHh][32 * 64];    // per-wave P (32 q); first 12KB reused as proj-A
  const int t = threadIdx.x;
  const int h = t >> 6;
  const int lane = t & 63;
  const int g = lane >> 4, l15 = lane & 15;
  int b = blockIdx.x;
  const int nb = gridDim.x;
  if ((nb & 7) == 0) b = (b & 7) * (nb >> 3) + (b >> 3);  // XCD chunked bijection
  const int wl = b >> 1;
  const int qh = b & 1;               // query half: rows qh*32 .. +32
  const f16* base = qkv + (size_t)wl * 64 * 576;

  {
    const f16* vr = base + (size_t)lane * 576 + 384 + h * 32;
    f16x8 vv[4];
#pragma unroll
    for (int u = 0; u < 4; ++u) vv[u] = *(const f16x8*)&vr[u * 8];
    const int c = lane >> 3, e7 = lane & 7;
#pragma unroll
    for (int u = 0; u < 4; ++u)
#pragma unroll
      for (int e = 0; e < 8; ++e) {
        int d = h * 32 + u * 8 + e;
        Vt[d * 64 + ((c ^ e) << 3) + e7] = vv[u][e];  // d&7 == e
      }
  }

  f16x8 qf[2], kf[4];
#pragma unroll
  for (int it = 0; it < 2; ++it)
    qf[it] = *(const f16x8*)&base[(size_t)(qh * 32 + it * 16 + l15) * 576 + h * 32 + g * 8];
#pragma unroll
  for (int jt = 0; jt < 4; ++jt)
    kf[jt] = *(const f16x8*)&base[(size_t)(jt * 16 + l15) * 576 + 192 + h * 32 + g * 8];

  f32x4 S[2][4];
#pragma unroll
  for (int it = 0; it < 2; ++it)
#pragma unroll
    for (int jt = 0; jt < 4; ++jt) S[it][jt] = (f32x4){0.f, 0.f, 0.f, 0.f};
#pragma unroll
  for (int it = 0; it < 2; ++it)
#pragma unroll
    for (int jt = 0; jt < 4; ++jt)
      S[it][jt] = __builtin_amdgcn_mfma_f32_16x16x32_f16(qf[it], kf[jt], S[it][jt], 0, 0, 0);

  const int wi = (w0 + wl) & 255;
  const int wh = wi >> 4, wwc = wi & 15;
  int regj[4];
#pragma unroll
  for (int jt = 0; jt < 4; ++jt) {
    int col = jt * 16 + l15;
    int rj = wh * 8 + (col >> 3), cj = wwc * 8 + (col & 7);
    regj[jt] = (rj < 120 ? 0 : rj < 124 ? 1 : 2) * 3 + (cj < 120 ? 0 : cj < 124 ? 1 : 2);
  }
#pragma unroll
  for (int it = 0; it < 2; ++it) {
    const int itg = qh * 2 + it;
    int regi[4];
#pragma unroll
    for (int r = 0; r < 4; ++r) {
      int row = itg * 16 + g * 4 + r;
      int ri = wh * 8 + (row >> 3), ci = wwc * 8 + (row & 7);
      regi[r] = (ri < 120 ? 0 : ri < 124 ? 1 : 2) * 3 + (ci < 120 ? 0 : ci < 124 ? 1 : 2);
    }
#pragma unroll
    for (int jt = 0; jt < 4; ++jt) {
      f32x4 bb = *(const f32x4*)&biasF2[(((h * 4 + itg) * 4 + jt) * 64 + lane) * 4];
#pragma unroll
      for (int r = 0; r < 4; ++r) {
        float v = S[it][jt][r] * QSCALE + bb[r];
        if (regi[r] != regj[jt]) v -= 100.f;
        S[it][jt][r] = v;
      }
    }
  }

#pragma unroll
  for (int it = 0; it < 2; ++it) {
#pragma unroll
    for (int r = 0; r < 4; ++r) {
      float m = fmaxf(fmaxf(S[it][0][r], S[it][1][r]), fmaxf(S[it][2][r], S[it][3][r]));
#pragma unroll
      for (int off = 1; off < 16; off <<= 1) m = fmaxf(m, __shfl_xor(m, off));
#pragma unroll
      for (int jt = 0; jt < 4; ++jt) S[it][jt][r] = __expf(S[it][jt][r] - m);
    }
  }

  f16* pb = &Pb[h][0];
#pragma unroll
  for (int it = 0; it < 2; ++it)
#pragma unroll
    for (int jt = 0; jt < 4; ++jt)
#pragma unroll
      for (int r = 0; r < 4; ++r) {
        int row = it * 16 + g * 4 + r;
        int cs = (jt * 2 + (l15 >> 3)) ^ (row & 7);
        pb[row * 64 + cs * 8 + (l15 & 7)] = (f16)S[it][jt][r];
      }

  f32x4 O[2][2], Ssum[2];
#pragma unroll
  for (int it = 0; it < 2; ++it) {
    O[it][0] = (f32x4){0.f, 0.f, 0.f, 0.f};
    O[it][1] = (f32x4){0.f, 0.f, 0.f, 0.f};
    Ssum[it] = (f32x4){0.f, 0.f, 0.f, 0.f};
  }
  f16x8 ones;
#pragma unroll
  for (int e = 0; e < 8; ++e) ones[e] = (f16)1.f;
#pragma unroll
  for (int jh = 0; jh < 2; ++jh) {
    const int csw = ((jh * 4 + g) ^ (l15 & 7)) << 3;
    f16x8 pf[2], vf[2];
#pragma unroll
    for (int it = 0; it < 2; ++it) pf[it] = *(const f16x8*)&pb[(it * 16 + l15) * 64 + csw];
#pragma unroll
    for (int dt = 0; dt < 2; ++dt) vf[dt] = *(const f16x8*)&Vt[(h * 32 + dt * 16 + l15) * 64 + csw];
#pragma unroll
    for (int it = 0; it < 2; ++it) {
      O[it][0] = __builtin_amdgcn_mfma_f32_16x16x32_f16(pf[it], vf[0], O[it][0], 0, 0, 0);
      O[it][1] = __builtin_amdgcn_mfma_f32_16x16x32_f16(pf[it], vf[1], O[it][1], 0, 0, 0);
      Ssum[it] = __builtin_amdgcn_mfma_f32_16x16x32_f16(pf[it], ones, Ssum[it], 0, 0, 0);
    }
  }

  __syncthreads();

  {
    char* Ao = (char*)&Pb[0][0];
#pragma unroll
    for (int it = 0; it < 2; ++it) {
      f32x4 rin;
#pragma unroll
      for (int r = 0; r < 4; ++r) rin[r] = 1.f / Ssum[it][r];
#pragma unroll
      for (int dt = 0; dt < 2; ++dt) {
        int hh = dt * 2 + (l15 >> 3);
        int e = l15 & 7;
#pragma unroll
        for (int r = 0; r < 4; ++r) {
          *(f16*)(Ao + (h * 2 + it) * 1024 + ((g * 4 + r) + hh * 16) * 16 + e * 2) =
              (f16)(O[it][dt][r] * rin[r]);
        }
      }
    }
  }
  __syncthreads();

  {
    const char* Ao = (const char*)&Pb[0][0];
    f32x4 acc[2][2];
#pragma unroll
    for (int i = 0; i < 2; ++i) {
      acc[i][0] = (f32x4){0.f, 0.f, 0.f, 0.f};
      acc[i][1] = (f32x4){0.f, 0.f, 0.f, 0.f};
    }
#pragma unroll
    for (int ks = 0; ks < 6; ++ks) {
      f16x8 bf[2];
#pragma unroll
      for (int ni = 0; ni < 2; ++ni)
        bf[ni] = *(const f16x8*)&Wpf[(((size_t)(h * 2 + ni) * 6 + ks) << 9) + (lane << 3)];
#pragma unroll
      for (int it = 0; it < 2; ++it) {
        f16x8 ah = *(const f16x8*)(Ao + (ks * 2 + it) * 1024 + lane * 16);
#pragma unroll
        for (int ni = 0; ni < 2; ++ni)
          acc[it][ni] = __builtin_amdgcn_mfma_f32_16x16x32_f16(ah, bf[ni], acc[it][ni], 0, 0, 0);
      }
    }
#pragma unroll
    for (int it = 0; it < 2; ++it)
#pragma unroll
      for (int ni = 0; ni < 2; ++ni) {
        int col = h * 32 + ni * 16 + l15;
        float bcol = pb_[col];
#pragma unroll
        for (int r = 0; r < 4; ++r) {
          int ml = qh * 32 + it * 16 + g * 4 + r;
          int dst = win_row_to_src((w0 + wl) * 64 + ml);
          out[(size_t)dst * 192 + col] = acc[it][ni][r] + bcol + resid[(size_t)dst * 192 + col];
        }
      }
  }
}

// ---------------- host launch ----------------
extern "C" void kernel_launch(void* const* d_in, const int* in_sizes, int n_in,
                              void* d_out, int out_size, void* d_ws, size_t ws_size,
                              hipStream_t stream) {
  const float* x     = (const float*)d_in[0];
  const float* ln1w  = (const float*)d_in[1];
  const float* ln1b  = (const float*)d_in[2];
  const float* qkvw  = (const float*)d_in[3];
  const float* qkvb  = (const float*)d_in[4];
  const float* rpb   = (const float*)d_in[5];
  const float* projw = (const float*)d_in[6];
  const float* projb = (const float*)d_in[7];
  const float* ln2w  = (const float*)d_in[8];
  const float* ln2b  = (const float*)d_in[9];
  const float* fc1w  = (const float*)d_in[10];
  const float* fc1b  = (const float*)d_in[11];
  const float* fc2w  = (const float*)d_in[12];
  const float* fc2b  = (const float*)d_in[13];
  float* out = (float*)d_out;

  // ws layout (B): biasF2 96K | Wf f16 frag-major | xh 48M | big
  char* ws = (char*)d_ws;
  float* biasF2 = (float*)ws;
  f16* qkvwF = (f16*)(ws + 98304);
  f16* projwF = (f16*)(ws + 319488);
  f16* fc1wF = (f16*)(ws + 393216);
  f16* fc2wF = (f16*)(ws + 688128);
  f16* xh    = (f16*)(ws + 983040);
  char* big  = ws + 983040 + 50331648;
  size_t R = ws_size > (size_t)(983040 + 50331648)
                 ? ws_size - (983040 + 50331648) : 0;

  long long wch = (long long)(R / 73728);  // per window: qkv16 only
  if (wch > NWINtot) wch = NWINtot;
  wch &= ~1LL;
  if (wch < 2) wch = 2;

  wconv_frag<<<432, 256, 0, stream>>>(qkvw, qkvwF, 192, 576);
  wconv_frag<<<144, 256, 0, stream>>>(projw, projwF, 192, 192);
  wconv_frag<<<576, 256, 0, stream>>>(fc1w, fc1wF, 192, 768);
  wconv_frag<<<576, 256, 0, stream>>>(fc2w, fc2wF, 768, 192);
  rpb_expand_kernel<<<96, 256, 0, stream>>>(rpb, biasF2);

  ln_prep_kernel<1><<<Mrows / 16, 256, 0, stream>>>(x, ln1w, ln1b, xh, 0);

  f16* qkvc = (f16*)big;
  for (int w = 0; w < NWINtot; w += (int)wch) {
    int cur = (NWINtot - w < (int)wch) ? (NWINtot - w) : (int)wch;
    int ny = cur * 64 / 128;
    gemm_mfma16<192, 576, 0><<<3 * ny, 512, 0, stream>>>(
        xh, qkvwF, qkvb, nullptr, qkvc, w * 64, 0, 3);
    attn_mfma<<<cur * 2, 384, 0, stream>>>(qkvc, biasF2, projwF, projb, x, out, w);
  }

  // fused LN2 + MLP (R17/R20 measured-best 4-wave version)
  mlp_fused<<<Mrows / 64, 256, 0, stream>>>(
      fc1wF, fc2wF, fc1b, fc2b, ln2w, ln2b, out);
}